// Round 14
// baseline (114.166 us; speedup 1.0000x reference)
//
#include <hip/hip_runtime.h>
#include <hip/hip_bf16.h>

// Non-backtracking random walk, 32 steps.
// out = [walks (steps+1,n) ; walk_edges (steps,n)] int32.
//
// R14 = R11 theory, smaller batch (8-step quarters instead of 16-step
// halves) after 3 identical-source container failures — minimal mutation to
// dodge any source-correlated trigger while still testing the theory:
// vmcnt is a FIFO (in-issue-order) counter, so a gather's s_waitcnt also
// waits for all OLDER stores (~600cyc HBM ack). Interleaving 4 stores with
// each step's gathers made the per-step chain ~2250cyc vs ~350cyc pure
// L2-hit gather. Fix: run each 8-step quarter with ZERO stores in the
// dependent chain (outputs in 32 registers), then flush 32 stores per
// quarter (drain amortized). Base config = R8/R10 best: stride-18 u16 rows
// w/ in-row hbits (3.6MB L2-resident), 2 chains/thread, predicated alt
// gather (P_bt=1/16), nontemporal streaming.
// Pack kernel verifies uniform CSR (deg==16, offset==16v, ids<2^17); on
// violation walker takes a fully-general fallback.

#define DEG 16
#define CHAINS 2

__global__ void pack_check_kernel(const int* __restrict__ adj_nodes,
                                  const int* __restrict__ adj_offset,
                                  const int* __restrict__ degrees,
                                  int n,
                                  unsigned int* __restrict__ pk32,  // 9 u32 per row (36B)
                                  int* __restrict__ flag) {
    int v = blockIdx.x * blockDim.x + threadIdx.x;
    if (v >= n) return;

    bool bad = (degrees[v] != DEG) || (adj_offset[v] != v * DEG);

    const uint4* row4 = (const uint4*)(adj_nodes + (size_t)v * DEG); // 64B-aligned
    uint4 r[4];
    r[0] = row4[0]; r[1] = row4[1]; r[2] = row4[2]; r[3] = row4[3];
    const unsigned* rr = (const unsigned*)r;

    unsigned wv[8];
    unsigned hbits = 0;
#pragma unroll
    for (int j = 0; j < 8; ++j) {
        unsigned u0 = rr[2 * j];
        unsigned u1 = rr[2 * j + 1];
        if (u0 >= 131072u || u1 >= 131072u) bad = true;   // needs >17 bits
        wv[j] = (u0 & 0xffffu) | ((u1 & 0xffffu) << 16);
        hbits |= ((u0 >> 16) & 1u) << (2 * j);
        hbits |= ((u1 >> 16) & 1u) << (2 * j + 1);
    }
    unsigned int* dst = pk32 + (size_t)v * 9;   // 36B/row, 4B-aligned
#pragma unroll
    for (int j = 0; j < 8; ++j) dst[j] = wv[j];
    dst[8] = hbits;                              // u16 hbits at r[16]

    if (bad) atomicOr(flag, 1);
}

template <int STEPS>
__global__ __launch_bounds__(64) void walker_fast2(
    const unsigned short* __restrict__ pk,   // stride-18 u16 rows
    const int* __restrict__ choices,
    int* __restrict__ out, int n, int h,
    const int* __restrict__ flag,
    const int* __restrict__ adj_nodes,
    const int* __restrict__ adj_offset,
    const int* __restrict__ degrees) {

    int t = blockIdx.x * blockDim.x + threadIdx.x;
    if (t >= h) return;

    int* walks      = out;                    // [STEPS+1, n]
    int* walk_edges = out + (STEPS + 1) * n;  // [STEPS, n]

    int w0 = t;
    int w1 = t + h;
    bool has1 = (w1 < n);
    int w1s = has1 ? w1 : w0;

    __builtin_nontemporal_store(w0, &walks[w0]);
    if (has1) __builtin_nontemporal_store(w1, &walks[w1]);

    if (*flag == 0) {
        // ---- fast path: 2 chains, predicated alt, store-free 8-step runs ----
        int prev0 = -1, cur0 = w0;
        int prev1 = -1, cur1 = w1s;

        static_assert(STEPS % 8 == 0, "");
#pragma unroll 1
        for (int q = 0; q < STEPS / 8; ++q) {
            // preload this quarter's choices (16 independent nt loads)
            int c0[8], c1[8];
#pragma unroll
            for (int i = 0; i < 8; ++i) {
                c0[i] = __builtin_nontemporal_load(&choices[(q * 8 + i) * n + w0]);
                c1[i] = __builtin_nontemporal_load(&choices[(q * 8 + i) * n + w1s]);
            }

            // run 8 steps with NO stores in the dependent chain
            int on0[8], oe0[8], on1[8], oe1[8];
#pragma unroll
            for (int i = 0; i < 8; ++i) {
                unsigned ch0 = (unsigned)c0[i];
                unsigned ch1 = (unsigned)c1[i];
                unsigned e0 = ch0 & (DEG - 1);
                unsigned e1 = ch1 & (DEG - 1);

                const unsigned short* r0 = pk + (unsigned)cur0 * 18u;
                const unsigned short* r1 = pk + (unsigned)cur1 * 18u;

                unsigned l00 = r0[e0];
                unsigned hb0 = r0[16];
                unsigned l10 = r1[e1];
                unsigned hb1 = r1[16];

                int n00 = (int)(l00 | (((hb0 >> e0) & 1u) << 16));
                int n10 = (int)(l10 | (((hb1 >> e1) & 1u) << 16));

                int nw0 = n00, nw1 = n10;
                unsigned ef0 = e0, ef1 = e1;
                if (n00 == prev0) {                     // ~1/16 of lanes
                    unsigned a0 = (e0 + 1u + ch0 % (DEG - 1)) & (DEG - 1);
                    unsigned l01 = r0[a0];
                    nw0 = (int)(l01 | (((hb0 >> a0) & 1u) << 16));
                    ef0 = a0;
                }
                if (n10 == prev1) {
                    unsigned a1 = (e1 + 1u + ch1 % (DEG - 1)) & (DEG - 1);
                    unsigned l11 = r1[a1];
                    nw1 = (int)(l11 | (((hb1 >> a1) & 1u) << 16));
                    ef1 = a1;
                }

                on0[i] = nw0; oe0[i] = (cur0 << 4) + (int)ef0;
                on1[i] = nw1; oe1[i] = (cur1 << 4) + (int)ef1;

                prev0 = cur0; cur0 = nw0;
                prev1 = cur1; cur1 = nw1;
            }

            // flush: 32 independent stores; drain overlaps next quarter
#pragma unroll
            for (int i = 0; i < 8; ++i) {
                int step = q * 8 + i;
                __builtin_nontemporal_store(on0[i], &walks[(step + 1) * n + w0]);
                __builtin_nontemporal_store(oe0[i], &walk_edges[step * n + w0]);
                if (has1) {
                    __builtin_nontemporal_store(on1[i], &walks[(step + 1) * n + w1]);
                    __builtin_nontemporal_store(oe1[i], &walk_edges[step * n + w1]);
                }
            }
        }
    } else {
        // ---- general fallback: 2 dependent gathers/step ----
        for (int k = 0; k < 2; ++k) {
            int w = (k == 0) ? w0 : w1;
            if (w >= n) break;
            int prev = -1, cur = w;
            for (int i = 0; i < STEPS; ++i) {
                int chv = choices[i * n + w];
                int deg = degrees[cur];
                int off = adj_offset[cur];
                int nb  = deg - 1 > 1 ? deg - 1 : 1;

                int e      = chv % deg;
                int chosen = off + e;
                int alt    = off + (e + 1 + chv % nb) % deg;

                int nv0 = adj_nodes[chosen];
                int nv1 = adj_nodes[alt];

                bool bt = (nv0 == prev);
                int nw  = bt ? nv1 : nv0;
                walks[(i + 1) * n + w] = nw;
                walk_edges[i * n + w]  = bt ? alt : chosen;
                prev = cur;
                cur  = nw;
            }
        }
    }
}

__global__ __launch_bounds__(256) void walker_generic(
    const int* __restrict__ adj_nodes,
    const int* __restrict__ adj_offset,
    const int* __restrict__ degrees,
    const int* __restrict__ choices,
    int* __restrict__ out, int n, int steps) {

    int w = blockIdx.x * blockDim.x + threadIdx.x;
    if (w >= n) return;

    int* walks      = out;
    int* walk_edges = out + (steps + 1) * n;
    walks[w] = w;

    int prev = -1, cur = w;
    for (int i = 0; i < steps; ++i) {
        int chv = choices[i * n + w];
        int deg = degrees[cur];
        int off = adj_offset[cur];
        int nb  = deg - 1 > 1 ? deg - 1 : 1;

        int e      = chv % deg;
        int chosen = off + e;
        int alt    = off + (e + 1 + chv % nb) % deg;

        int nv0 = adj_nodes[chosen];
        int nv1 = adj_nodes[alt];

        bool bt = (nv0 == prev);
        int nw  = bt ? nv1 : nv0;
        walks[(i + 1) * n + w] = nw;
        walk_edges[i * n + w]  = bt ? alt : chosen;
        prev = cur;
        cur  = nw;
    }
}

extern "C" void kernel_launch(void* const* d_in, const int* in_sizes, int n_in,
                              void* d_out, int out_size, void* d_ws, size_t ws_size,
                              hipStream_t stream) {
    // inputs: 0=x (unused), 1=adj_nodes, 2=adj_offset, 3=degrees, 4=choices
    const int* adj_nodes  = (const int*)d_in[1];
    const int* adj_offset = (const int*)d_in[2];
    const int* degrees    = (const int*)d_in[3];
    const int* choices    = (const int*)d_in[4];
    int* out = (int*)d_out;

    int n     = in_sizes[2];
    int steps = in_sizes[4] / n;

    // ws layout: [0,4) flag | [64, 64+36n) packed stride-18 rows
    size_t pk_off = 64;
    size_t need   = pk_off + (size_t)n * 36;

    if (steps == 32 && ws_size >= need) {
        int* flag = (int*)d_ws;
        unsigned int*   pk32 = (unsigned int*)((char*)d_ws + pk_off);
        unsigned short* pk   = (unsigned short*)pk32;

        hipMemsetAsync(flag, 0, sizeof(int), stream);
        int pb = 256, pg = (n + pb - 1) / pb;
        pack_check_kernel<<<pg, pb, 0, stream>>>(adj_nodes, adj_offset, degrees,
                                                 n, pk32, flag);
        int h  = (n + CHAINS - 1) / CHAINS;
        int wb = 64, wg = (h + wb - 1) / wb;
        walker_fast2<32><<<wg, wb, 0, stream>>>(pk, choices, out, n, h, flag,
                                                adj_nodes, adj_offset, degrees);
    } else {
        int block = 256, grid = (n + block - 1) / block;
        walker_generic<<<grid, block, 0, stream>>>(adj_nodes, adj_offset,
                                                   degrees, choices, out, n, steps);
    }
}